// Round 8
// baseline (130.671 us; speedup 1.0000x reference)
//
#include <hip/hip_runtime.h>
#include <stdint.h>

#define EPSN 1e-12f

typedef float f32x16 __attribute__((ext_vector_type(16)));
typedef float f32x4 __attribute__((ext_vector_type(4)));
typedef __bf16 bf16x8 __attribute__((ext_vector_type(8)));
typedef unsigned short u16x4 __attribute__((ext_vector_type(4)));

// ---- bf16 helpers ----
__device__ __forceinline__ unsigned short f2bf(float f) {
  union { float f; unsigned int u; } v; v.f = f;
  unsigned int u = v.u + 0x7FFFu + ((v.u >> 16) & 1u);
  return (unsigned short)(u >> 16);
}
__device__ __forceinline__ float bf2f(unsigned short h) {
  union { float f; unsigned int u; } v; v.u = ((unsigned int)h) << 16;
  return v.f;
}

// ---- workspace layout (ushort offsets) ----
// Fragment-major packed weights for 32x32x16 MFMA, K padded 258(+bias)->272:
//   addr = ((tile*NKS + ks)*64 + hi*32 + col)*8 + j
//   value = W[o = tile*32 + col][k = ks*16 + hi*8 + j]  (k=258 bias, >258 zero)
#define NKS 17
#define WQF_OFF 0
#define WKF_OFF (32 * NKS * 64 * 8)
#define WVP_OFF (2 * 32 * NKS * 64 * 8)

// =====================================================================
// prep v8: NON-TEMPORAL stores. Theory: regular stores leave the 2.2 MB
// packed-weight lines DIRTY, scattered over all 8 XCD L2s; fused's reads
// from every XCD then hit the remote-dirty snoop path (slow, invariant
// to all scheduling) for 7/8 of lines. nt stores push weights to L3
// clean, so fused first-touch allocates them in the LOCAL L2.
// =====================================================================
__global__ __launch_bounds__(256) void prep_kernel(
    const float* __restrict__ wq, const float* __restrict__ bq,
    const float* __restrict__ wk, const float* __restrict__ bk,
    const float* __restrict__ v, const float* __restrict__ wout,
    unsigned short* __restrict__ wsp) {
  int bid = blockIdx.x;
  if (bid < 512) {
    int isK = bid >= 256;
    int ob = (bid & 255) * 4;
    const float* w = isK ? wk : wq;
    const float* bb = isK ? bk : bq;
    unsigned short* dst = wsp + (isK ? WKF_OFF : WQF_OFF);
    for (int i = threadIdx.x; i < 4 * 129; i += 256) {
      int r = i / 129, q = i - r * 129;
      int o = ob + r, k = q * 2;
      float2 w2;
      w2.x = __builtin_nontemporal_load(w + o * 258 + k);
      w2.y = __builtin_nontemporal_load(w + o * 258 + k + 1);
      int g = o >> 5, col = o & 31;
      int ks = k >> 4, hi = (k >> 3) & 1, j = k & 7;
      uint32_t pk = (uint32_t)f2bf(w2.x) | ((uint32_t)f2bf(w2.y) << 16);
      __builtin_nontemporal_store(
          pk, (uint32_t*)(dst + (((g * NKS + ks) * 64 + hi * 32 + col) << 3) + j));
    }
    for (int i = threadIdx.x; i < 4 * 14; i += 256) {
      int r = i / 14, kk = 258 + (i - r * 14);
      int o = ob + r;
      int g = o >> 5, col = o & 31;
      int ks = kk >> 4, hi = (kk >> 3) & 1, j = kk & 7;
      unsigned short val = (kk == 258) ? f2bf(bb[o]) : (unsigned short)0;
      __builtin_nontemporal_store(
          val, dst + (((g * NKS + ks) * 64 + hi * 32 + col) << 3) + j);
    }
  } else {
    int idx = (bid - 512) * 256 + threadIdx.x;
    int fc = idx & 15, m = (idx >> 4) & 63, o = idx >> 10;
    const f32x4* wo = (const f32x4*)(wout + o * 256 + fc * 16);
    const f32x4* vm = (const f32x4*)(v + m * 256 + fc * 16);
    float s = 0.f;
#pragma unroll
    for (int f = 0; f < 4; ++f) {
      f32x4 a = __builtin_nontemporal_load(wo + f);
      f32x4 bvv = __builtin_nontemporal_load(vm + f);
      s += a[0]*bvv[0] + a[1]*bvv[1] + a[2]*bvv[2] + a[3]*bvv[3];
    }
    s += __shfl_xor(s, 1, 64);
    s += __shfl_xor(s, 2, 64);
    s += __shfl_xor(s, 4, 64);
    s += __shfl_xor(s, 8, 64);
    if (fc == 0)
      __builtin_nontemporal_store(f2bf(s), wsp + WVP_OFF + o * 64 + m);
  }
}

// =====================================================================
// fused v8 = v7 (nt x-loads / out-stores, depth-3 ring, ks-rotation,
// LDS-epilogue) + s_setprio(1) around the MFMA cluster (barrier-free
// K-loop => waves are role-diverse; scheduler can favor MFMA-ready waves).
// =====================================================================
#define PXB 64   // pixels per block
#define KP 296   // xp row stride in shorts
#define QS 66    // qbar row stride (floats)
#define AT 72    // attnM row stride (shorts)

__global__ __launch_bounds__(1024, 4) void fused_kernel(
    const float* __restrict__ x, const float* __restrict__ pos,
    const unsigned short* __restrict__ wsp, const float* __restrict__ bout,
    float* __restrict__ out) {
  __shared__ __align__(16) unsigned short xp[PXB * KP];        // 37888 B
  __shared__ __align__(16) float qbarL[16 * QS];               // 4224 B
  __shared__ __align__(16) unsigned short attnM[PXB * AT];     // 9216 B
  __shared__ float boutL[256];                                 // 1024 B

  const int tid = threadIdx.x;
  const int lane = tid & 63;
  const int wid = __builtin_amdgcn_readfirstlane(tid >> 6);
  const int px = lane & 31, q2 = lane >> 5;
  const int P0 = blockIdx.x * PXB;
  const int b = P0 >> 12, s0 = P0 & 4095;

  // Per-wave A-stream bases (tile0 = 2*wid, tile1 = 2*wid+1; +lane frag)
  const int wtoff = (2 * wid) * NKS * 512 + lane * 8;
  const unsigned short* wqf = wsp + WQF_OFF + wtoff;
  const unsigned short* wkf = wsp + WKF_OFF + wtoff;

  const int kbase = wid;  // 0..15 < NKS: per-wave K-slice rotation

  bf16x8 ring0[3], ring1[3];
#define RING_FILL(WB) do {                                                \
    _Pragma("unroll")                                                     \
    for (int s = 0; s < 3; ++s) {                                         \
      int kp = kbase + s; if (kp >= NKS) kp -= NKS;                       \
      ring0[s] = *(const bf16x8*)((WB) + kp * 512);                       \
      ring1[s] = *(const bf16x8*)((WB) + NKS * 512 + kp * 512);           \
    }                                                                     \
  } while (0)

  // q-ring fill issued first: L3/L2 latency hides under the staging phase.
  RING_FILL(wqf);

  // ---- stage xp[p][c] via float4 nt loads (16B/lane, coalesced) ----
  uint32_t* xp32 = (uint32_t*)xp;
  {
    const float* xrow = x + b * 256 * 4096 + s0;
    f32x4 lo[2], hi[2];
#pragma unroll
    for (int it = 0; it < 2; ++it) {
      int idx = tid + it * 1024;                  // 0..2047
      int g = idx & 15, dcol = idx >> 4;          // dcol 0..127
      lo[it] = __builtin_nontemporal_load(
          (const f32x4*)(xrow + (2 * dcol) * 4096 + 4 * g));
      hi[it] = __builtin_nontemporal_load(
          (const f32x4*)(xrow + (2 * dcol + 1) * 4096 + 4 * g));
    }
#pragma unroll
    for (int it = 0; it < 2; ++it) {
      int idx = tid + it * 1024;
      int g = idx & 15, dcol = idx >> 4;
#pragma unroll
      for (int j = 0; j < 4; ++j) {
        int pp = 4 * g + j;
        xp32[pp * 148 + dcol] =
            (uint32_t)f2bf(lo[it][j]) | ((uint32_t)f2bf(hi[it][j]) << 16);
      }
    }
    // tail cols: dcol 128 = (pos_y,pos_x), 129 = (1,0) bias, 130..135 = 0
    if (tid < 512) {
      int pp = tid & 63, dcol = 128 + (tid >> 6);
      float t0 = 0.f, t1 = 0.f;
      if (dcol == 128) { t0 = pos[s0 + pp]; t1 = pos[4096 + s0 + pp]; }
      else if (dcol == 129) { t0 = 1.0f; }
      xp32[pp * 148 + dcol] = (uint32_t)f2bf(t0) | ((uint32_t)f2bf(t1) << 16);
    }
  }
  if (tid < 256) boutL[tid] = bout[tid];
  for (int i = tid; i < 16 * QS; i += 1024) qbarL[i] = 0.f;
  __syncthreads();

// K-loop: rotated slice order (kbase+i mod 17), depth-3 register ring,
// fully unrolled => ring index i%3 static. setprio around MFMA cluster.
#define PHASE(WB) do {                                                    \
    _Pragma("unroll")                                                     \
    for (int i = 0; i < NKS; ++i) {                                       \
      int ks = kbase + i; if (ks >= NKS) ks -= NKS;                       \
      bf16x8 _A0 = ring0[i % 3], _A1 = ring1[i % 3];                      \
      if (i + 3 < NKS) {                                                  \
        int kp = ks + 3; if (kp >= NKS) kp -= NKS;                        \
        ring0[i % 3] = *(const bf16x8*)((WB) + kp * 512);                 \
        ring1[i % 3] = *(const bf16x8*)((WB) + NKS * 512 + kp * 512);     \
      }                                                                   \
      const int boff = ks * 16 + q2 * 8;                                  \
      bf16x8 _b0 = *(const bf16x8*)&xp[px * KP + boff];                   \
      bf16x8 _b1 = *(const bf16x8*)&xp[(32 + px) * KP + boff];            \
      __builtin_amdgcn_s_setprio(1);                                      \
      acc00 = __builtin_amdgcn_mfma_f32_32x32x16_bf16(_A0, _b0, acc00, 0, 0, 0); \
      acc01 = __builtin_amdgcn_mfma_f32_32x32x16_bf16(_A0, _b1, acc01, 0, 0, 0); \
      acc10 = __builtin_amdgcn_mfma_f32_32x32x16_bf16(_A1, _b0, acc10, 0, 0, 0); \
      acc11 = __builtin_amdgcn_mfma_f32_32x32x16_bf16(_A1, _b1, acc11, 0, 0, 0); \
      __builtin_amdgcn_s_setprio(0);                                      \
    }                                                                     \
  } while (0)

  // ================= q phase =================
  f32x16 acc00 = (f32x16)0.f, acc01 = (f32x16)0.f,
         acc10 = (f32x16)0.f, acc11 = (f32x16)0.f;
  PHASE(wqf);

  // k-ring fill: latency hides under the norm section below.
  RING_FILL(wkf);

  // normalize per m; accumulate qbar partials
  {
    float qsum[2][8];
#pragma unroll
    for (int nt = 0; nt < 2; ++nt)
#pragma unroll
      for (int r = 0; r < 8; ++r) qsum[nt][r] = 0.f;
#pragma unroll
    for (int ot = 0; ot < 2; ++ot) {
#pragma unroll
      for (int nt = 0; nt < 2; ++nt) {
        const f32x16 a = ot ? (nt ? acc11 : acc10) : (nt ? acc01 : acc00);
        float s20 = 0.f, s21 = 0.f;
#pragma unroll
        for (int r = 0; r < 8; ++r) {
          s20 = fmaf(a[r], a[r], s20);
          s21 = fmaf(a[r + 8], a[r + 8], s21);
        }
        s20 += __shfl_xor(s20, 32, 64);
        s21 += __shfl_xor(s21, 32, 64);
        float i0 = 1.0f / fmaxf(sqrtf(s20), EPSN);
        float i1 = 1.0f / fmaxf(sqrtf(s21), EPSN);
#pragma unroll
        for (int r = 0; r < 8; ++r) qsum[nt][r] += a[r] * i0 + a[r + 8] * i1;
      }
    }
#pragma unroll
    for (int nt = 0; nt < 2; ++nt)
#pragma unroll
      for (int r = 0; r < 8; ++r) {
        int j = (r & 3) + ((r >> 2) << 3) + (q2 << 2);
        atomicAdd(&qbarL[j * QS + nt * 32 + px], qsum[nt][r] * (1.0f / 64.0f));
      }
  }
  // NO barrier here: k-phase MFMAs don't read qbarL; the barrier below
  // (after the k K-loop) orders the qbar atomics vs the qb reads.

  // ================= k phase =================
  acc00 = (f32x16)0.f; acc01 = (f32x16)0.f;
  acc10 = (f32x16)0.f; acc11 = (f32x16)0.f;
  PHASE(wkf);
  __syncthreads();

  {
    float qb[2][8];
#pragma unroll
    for (int nt = 0; nt < 2; ++nt)
#pragma unroll
      for (int r = 0; r < 8; ++r) {
        int j = (r & 3) + ((r >> 2) << 3) + (q2 << 2);
        qb[nt][r] = qbarL[j * QS + nt * 32 + px];
      }
#pragma unroll
    for (int ot = 0; ot < 2; ++ot) {
#pragma unroll
      for (int nt = 0; nt < 2; ++nt) {
        const f32x16 a = ot ? (nt ? acc11 : acc10) : (nt ? acc01 : acc00);
        float s20 = 0.f, s21 = 0.f, sp0 = 0.f, sp1 = 0.f;
#pragma unroll
        for (int r = 0; r < 8; ++r) {
          s20 = fmaf(a[r], a[r], s20);         sp0 = fmaf(qb[nt][r], a[r], sp0);
          s21 = fmaf(a[r + 8], a[r + 8], s21); sp1 = fmaf(qb[nt][r], a[r + 8], sp1);
        }
        s20 += __shfl_xor(s20, 32, 64);
        s21 += __shfl_xor(s21, 32, 64);
        sp0 += __shfl_xor(sp0, 32, 64);
        sp1 += __shfl_xor(sp1, 32, 64);
        if (q2 == 0) {
          int m0 = wid * 4 + ot * 2;
          attnM[(nt * 32 + px) * AT + m0]     = f2bf(sp0 / fmaxf(sqrtf(s20), EPSN));
          attnM[(nt * 32 + px) * AT + m0 + 1] = f2bf(sp1 / fmaxf(sqrtf(s21), EPSN));
        }
      }
    }
  }
  __syncthreads();

  // ======= epilogue: out = x + bout + WVt @ attn (x from xp; nt stores) =======
  {
    const int otile = wid >> 1, pxt = wid & 1;
    f32x16 e = (f32x16)0.f;
    const unsigned short* wv = wsp + WVP_OFF + (otile * 32 + px) * 64 + q2 * 8;
    const unsigned short* ab = &attnM[(pxt * 32 + px) * AT + q2 * 8];
#pragma unroll
    for (int ks = 0; ks < 4; ++ks) {
      bf16x8 av = *(const bf16x8*)(wv + ks * 16);
      bf16x8 bv = *(const bf16x8*)(ab + ks * 16);
      e = __builtin_amdgcn_mfma_f32_32x32x16_bf16(av, bv, e, 0, 0, 0);
    }
    const int p = pxt * 32 + px;
    const unsigned short* xl = &xp[p * KP + otile * 32 + (q2 << 2)];
#pragma unroll
    for (int rq = 0; rq < 4; ++rq) {
      u16x4 xq = *(const u16x4*)(xl + 8 * rq);
#pragma unroll
      for (int j = 0; j < 4; ++j) {
        const int r = rq * 4 + j;
        const int o = otile * 32 + j + (rq << 3) + (q2 << 2);
        const int gi = (b * 256 + o) * 4096 + s0 + p;
        __builtin_nontemporal_store(bf2f(xq[j]) + boutL[o] + e[r], &out[gi]);
      }
    }
  }
#undef PHASE
#undef RING_FILL
}

// =====================================================================
extern "C" void kernel_launch(void* const* d_in, const int* in_sizes, int n_in,
                              void* d_out, int out_size, void* d_ws, size_t ws_size,
                              hipStream_t stream) {
  const float* x    = (const float*)d_in[0];
  const float* pos  = (const float*)d_in[1];
  const float* wq   = (const float*)d_in[2];
  const float* bq   = (const float*)d_in[3];
  const float* wk   = (const float*)d_in[4];
  const float* bk   = (const float*)d_in[5];
  const float* v    = (const float*)d_in[6];
  const float* wout = (const float*)d_in[7];
  const float* bout = (const float*)d_in[8];
  float* out = (float*)d_out;
  unsigned short* wsp = (unsigned short*)d_ws;

  hipLaunchKernelGGL(prep_kernel, dim3(1536), dim3(256), 0, stream,
                     wq, bq, wk, bk, v, wout, wsp);
  hipLaunchKernelGGL(fused_kernel, dim3(256), dim3(1024), 0, stream,
                     x, pos, wsp, bout, out);
}

// Round 9
// 127.826 us; speedup vs baseline: 1.0223x; 1.0223x over previous
//
#include <hip/hip_runtime.h>
#include <stdint.h>

#define EPSN 1e-12f

typedef float f32x16 __attribute__((ext_vector_type(16)));
typedef float f32x4 __attribute__((ext_vector_type(4)));
typedef __bf16 bf16x8 __attribute__((ext_vector_type(8)));
typedef unsigned short u16x4 __attribute__((ext_vector_type(4)));

// ---- bf16 helpers ----
__device__ __forceinline__ unsigned short f2bf(float f) {
  union { float f; unsigned int u; } v; v.f = f;
  unsigned int u = v.u + 0x7FFFu + ((v.u >> 16) & 1u);
  return (unsigned short)(u >> 16);
}
__device__ __forceinline__ float bf2f(unsigned short h) {
  union { float f; unsigned int u; } v; v.u = ((unsigned int)h) << 16;
  return v.f;
}

// ---- workspace layout (ushort offsets) ----
// Fragment-major packed weights for 32x32x16 MFMA, K padded 258(+bias)->272:
//   addr = ((tile*NKS + ks)*64 + hi*32 + col)*8 + j
//   value = W[o = tile*32 + col][k = ks*16 + hi*8 + j]  (k=258 bias, >258 zero)
#define NKS 17
#define WQF_OFF 0
#define WKF_OFF (32 * NKS * 64 * 8)
#define WVP_OFF (2 * 32 * NKS * 64 * 8)

// =====================================================================
// prep: blocks [0,512) pack wq/wk (4 o-rows each); [512,1536) WVt.
// (plain stores — nt-prep measured negative in R8)
// =====================================================================
__global__ __launch_bounds__(256) void prep_kernel(
    const float* __restrict__ wq, const float* __restrict__ bq,
    const float* __restrict__ wk, const float* __restrict__ bk,
    const float* __restrict__ v, const float* __restrict__ wout,
    unsigned short* __restrict__ wsp) {
  int bid = blockIdx.x;
  if (bid < 512) {
    int isK = bid >= 256;
    int ob = (bid & 255) * 4;
    const float* w = isK ? wk : wq;
    const float* bb = isK ? bk : bq;
    unsigned short* dst = wsp + (isK ? WKF_OFF : WQF_OFF);
    for (int i = threadIdx.x; i < 4 * 129; i += 256) {
      int r = i / 129, q = i - r * 129;
      int o = ob + r, k = q * 2;
      float2 w2 = *(const float2*)(w + o * 258 + k);
      int g = o >> 5, col = o & 31;
      int ks = k >> 4, hi = (k >> 3) & 1, j = k & 7;
      uint32_t pk = (uint32_t)f2bf(w2.x) | ((uint32_t)f2bf(w2.y) << 16);
      *(uint32_t*)(dst + (((g * NKS + ks) * 64 + hi * 32 + col) << 3) + j) = pk;
    }
    for (int i = threadIdx.x; i < 4 * 14; i += 256) {
      int r = i / 14, kk = 258 + (i - r * 14);
      int o = ob + r;
      int g = o >> 5, col = o & 31;
      int ks = kk >> 4, hi = (kk >> 3) & 1, j = kk & 7;
      dst[(((g * NKS + ks) * 64 + hi * 32 + col) << 3) + j] =
          (kk == 258) ? f2bf(bb[o]) : (unsigned short)0;
    }
  } else {
    int idx = (bid - 512) * 256 + threadIdx.x;
    int fc = idx & 15, m = (idx >> 4) & 63, o = idx >> 10;
    const f32x4* wo = (const f32x4*)(wout + o * 256 + fc * 16);
    const f32x4* vm = (const f32x4*)(v + m * 256 + fc * 16);
    float s = 0.f;
#pragma unroll
    for (int f = 0; f < 4; ++f) {
      f32x4 a = wo[f], bvv = vm[f];
      s += a[0]*bvv[0] + a[1]*bvv[1] + a[2]*bvv[2] + a[3]*bvv[3];
    }
    s += __shfl_xor(s, 1, 64);
    s += __shfl_xor(s, 2, 64);
    s += __shfl_xor(s, 4, 64);
    s += __shfl_xor(s, 8, 64);
    if (fc == 0) wsp[WVP_OFF + o * 64 + m] = f2bf(s);
  }
}

// =====================================================================
// fused v9: ROLLED K-loop (#pragma unroll 1), ~16-instruction body:
// depth-1 prefetch in NAMED regs (A0c/A1c current, A0n/A1n next),
// pointer-increment addressing, no mod-17, no ring arrays. Theory:
// the fully-unrolled 17-iter macro-bodies at the exact 128-reg cap
// defeat the compiler's scheduler (m141 regime) -> uniform exposed
// latency per iteration, invariant to all manual prefetch schemes.
// Small rolled body + ~20 free VGPRs restores compiler pipelining.
// Keeps: nt x-loads/out-stores, LDS epilogue, no-barrier qbar trick.
// =====================================================================
#define PXB 64   // pixels per block
#define KP 296   // xp row stride in shorts
#define QS 66    // qbar row stride (floats)
#define AT 72    // attnM row stride (shorts)

__global__ __launch_bounds__(1024, 4) void fused_kernel(
    const float* __restrict__ x, const float* __restrict__ pos,
    const unsigned short* __restrict__ wsp, const float* __restrict__ bout,
    float* __restrict__ out) {
  __shared__ __align__(16) unsigned short xp[PXB * KP];        // 37888 B
  __shared__ __align__(16) float qbarL[16 * QS];               // 4224 B
  __shared__ __align__(16) unsigned short attnM[PXB * AT];     // 9216 B
  __shared__ float boutL[256];                                 // 1024 B

  const int tid = threadIdx.x;
  const int lane = tid & 63;
  const int wid = __builtin_amdgcn_readfirstlane(tid >> 6);
  const int px = lane & 31, q2 = lane >> 5;
  const int P0 = blockIdx.x * PXB;
  const int b = P0 >> 12, s0 = P0 & 4095;

  // Per-wave A-stream bases (tile0 = 2*wid, tile1 = 2*wid+1; +lane frag)
  const int wtoff = (2 * wid) * NKS * 512 + lane * 8;
  const unsigned short* wqf = wsp + WQF_OFF + wtoff;
  const unsigned short* wkf = wsp + WKF_OFF + wtoff;

  // ---- stage xp[p][c] via float4 nt loads (16B/lane, coalesced) ----
  uint32_t* xp32 = (uint32_t*)xp;
  {
    const float* xrow = x + b * 256 * 4096 + s0;
    f32x4 lo[2], hi[2];
#pragma unroll
    for (int it = 0; it < 2; ++it) {
      int idx = tid + it * 1024;                  // 0..2047
      int g = idx & 15, dcol = idx >> 4;          // dcol 0..127
      lo[it] = __builtin_nontemporal_load(
          (const f32x4*)(xrow + (2 * dcol) * 4096 + 4 * g));
      hi[it] = __builtin_nontemporal_load(
          (const f32x4*)(xrow + (2 * dcol + 1) * 4096 + 4 * g));
    }
#pragma unroll
    for (int it = 0; it < 2; ++it) {
      int idx = tid + it * 1024;
      int g = idx & 15, dcol = idx >> 4;
#pragma unroll
      for (int j = 0; j < 4; ++j) {
        int pp = 4 * g + j;
        xp32[pp * 148 + dcol] =
            (uint32_t)f2bf(lo[it][j]) | ((uint32_t)f2bf(hi[it][j]) << 16);
      }
    }
    // tail cols: dcol 128 = (pos_y,pos_x), 129 = (1,0) bias, 130..135 = 0
    if (tid < 512) {
      int pp = tid & 63, dcol = 128 + (tid >> 6);
      float t0 = 0.f, t1 = 0.f;
      if (dcol == 128) { t0 = pos[s0 + pp]; t1 = pos[4096 + s0 + pp]; }
      else if (dcol == 129) { t0 = 1.0f; }
      xp32[pp * 148 + dcol] = (uint32_t)f2bf(t0) | ((uint32_t)f2bf(t1) << 16);
    }
  }
  if (tid < 256) boutL[tid] = bout[tid];
  for (int i = tid; i < 16 * QS; i += 1024) qbarL[i] = 0.f;
  __syncthreads();

// Rolled K-loop: depth-1 named-register prefetch, tiny body, compiler-
// scheduled. Last iteration peeled (no over-read of the weight buffer).
#define PHASE(WB) do {                                                    \
    const unsigned short* _p0 = (WB);                                     \
    const unsigned short* _p1 = (WB) + NKS * 512;                         \
    const unsigned short* _bp0 = &xp[px * KP + q2 * 8];                   \
    const unsigned short* _bp1 = &xp[(32 + px) * KP + q2 * 8];            \
    bf16x8 _A0c = *(const bf16x8*)_p0;                                    \
    bf16x8 _A1c = *(const bf16x8*)_p1;                                    \
    _Pragma("unroll 1")                                                   \
    for (int i = 0; i < NKS - 1; ++i) {                                   \
      bf16x8 _A0n = *(const bf16x8*)(_p0 + (i + 1) * 512);                \
      bf16x8 _A1n = *(const bf16x8*)(_p1 + (i + 1) * 512);                \
      bf16x8 _b0 = *(const bf16x8*)(_bp0 + i * 16);                       \
      bf16x8 _b1 = *(const bf16x8*)(_bp1 + i * 16);                       \
      __builtin_amdgcn_s_setprio(1);                                      \
      acc00 = __builtin_amdgcn_mfma_f32_32x32x16_bf16(_A0c, _b0, acc00, 0, 0, 0); \
      acc01 = __builtin_amdgcn_mfma_f32_32x32x16_bf16(_A0c, _b1, acc01, 0, 0, 0); \
      acc10 = __builtin_amdgcn_mfma_f32_32x32x16_bf16(_A1c, _b0, acc10, 0, 0, 0); \
      acc11 = __builtin_amdgcn_mfma_f32_32x32x16_bf16(_A1c, _b1, acc11, 0, 0, 0); \
      __builtin_amdgcn_s_setprio(0);                                      \
      _A0c = _A0n; _A1c = _A1n;                                           \
    }                                                                     \
    {                                                                     \
      bf16x8 _b0 = *(const bf16x8*)(_bp0 + (NKS - 1) * 16);               \
      bf16x8 _b1 = *(const bf16x8*)(_bp1 + (NKS - 1) * 16);               \
      acc00 = __builtin_amdgcn_mfma_f32_32x32x16_bf16(_A0c, _b0, acc00, 0, 0, 0); \
      acc01 = __builtin_amdgcn_mfma_f32_32x32x16_bf16(_A0c, _b1, acc01, 0, 0, 0); \
      acc10 = __builtin_amdgcn_mfma_f32_32x32x16_bf16(_A1c, _b0, acc10, 0, 0, 0); \
      acc11 = __builtin_amdgcn_mfma_f32_32x32x16_bf16(_A1c, _b1, acc11, 0, 0, 0); \
    }                                                                     \
  } while (0)

  // ================= q phase =================
  f32x16 acc00 = (f32x16)0.f, acc01 = (f32x16)0.f,
         acc10 = (f32x16)0.f, acc11 = (f32x16)0.f;
  PHASE(wqf);

  // normalize per m; accumulate qbar partials
  {
    float qsum[2][8];
#pragma unroll
    for (int nt = 0; nt < 2; ++nt)
#pragma unroll
      for (int r = 0; r < 8; ++r) qsum[nt][r] = 0.f;
#pragma unroll
    for (int ot = 0; ot < 2; ++ot) {
#pragma unroll
      for (int nt = 0; nt < 2; ++nt) {
        const f32x16 a = ot ? (nt ? acc11 : acc10) : (nt ? acc01 : acc00);
        float s20 = 0.f, s21 = 0.f;
#pragma unroll
        for (int r = 0; r < 8; ++r) {
          s20 = fmaf(a[r], a[r], s20);
          s21 = fmaf(a[r + 8], a[r + 8], s21);
        }
        s20 += __shfl_xor(s20, 32, 64);
        s21 += __shfl_xor(s21, 32, 64);
        float i0 = 1.0f / fmaxf(sqrtf(s20), EPSN);
        float i1 = 1.0f / fmaxf(sqrtf(s21), EPSN);
#pragma unroll
        for (int r = 0; r < 8; ++r) qsum[nt][r] += a[r] * i0 + a[r + 8] * i1;
      }
    }
#pragma unroll
    for (int nt = 0; nt < 2; ++nt)
#pragma unroll
      for (int r = 0; r < 8; ++r) {
        int j = (r & 3) + ((r >> 2) << 3) + (q2 << 2);
        atomicAdd(&qbarL[j * QS + nt * 32 + px], qsum[nt][r] * (1.0f / 64.0f));
      }
  }
  // NO barrier here: k-phase MFMAs don't read qbarL; the barrier below
  // (after the k K-loop) orders the qbar atomics vs the qb reads.

  // ================= k phase =================
  acc00 = (f32x16)0.f; acc01 = (f32x16)0.f;
  acc10 = (f32x16)0.f; acc11 = (f32x16)0.f;
  PHASE(wkf);
  __syncthreads();

  {
    float qb[2][8];
#pragma unroll
    for (int nt = 0; nt < 2; ++nt)
#pragma unroll
      for (int r = 0; r < 8; ++r) {
        int j = (r & 3) + ((r >> 2) << 3) + (q2 << 2);
        qb[nt][r] = qbarL[j * QS + nt * 32 + px];
      }
#pragma unroll
    for (int ot = 0; ot < 2; ++ot) {
#pragma unroll
      for (int nt = 0; nt < 2; ++nt) {
        const f32x16 a = ot ? (nt ? acc11 : acc10) : (nt ? acc01 : acc00);
        float s20 = 0.f, s21 = 0.f, sp0 = 0.f, sp1 = 0.f;
#pragma unroll
        for (int r = 0; r < 8; ++r) {
          s20 = fmaf(a[r], a[r], s20);         sp0 = fmaf(qb[nt][r], a[r], sp0);
          s21 = fmaf(a[r + 8], a[r + 8], s21); sp1 = fmaf(qb[nt][r], a[r + 8], sp1);
        }
        s20 += __shfl_xor(s20, 32, 64);
        s21 += __shfl_xor(s21, 32, 64);
        sp0 += __shfl_xor(sp0, 32, 64);
        sp1 += __shfl_xor(sp1, 32, 64);
        if (q2 == 0) {
          int m0 = wid * 4 + ot * 2;
          attnM[(nt * 32 + px) * AT + m0]     = f2bf(sp0 / fmaxf(sqrtf(s20), EPSN));
          attnM[(nt * 32 + px) * AT + m0 + 1] = f2bf(sp1 / fmaxf(sqrtf(s21), EPSN));
        }
      }
    }
  }
  __syncthreads();

  // ======= epilogue: out = x + bout + WVt @ attn (x from xp; nt stores) =======
  {
    const int otile = wid >> 1, pxt = wid & 1;
    f32x16 e = (f32x16)0.f;
    const unsigned short* wv = wsp + WVP_OFF + (otile * 32 + px) * 64 + q2 * 8;
    const unsigned short* ab = &attnM[(pxt * 32 + px) * AT + q2 * 8];
#pragma unroll
    for (int ks = 0; ks < 4; ++ks) {
      bf16x8 av = *(const bf16x8*)(wv + ks * 16);
      bf16x8 bv = *(const bf16x8*)(ab + ks * 16);
      e = __builtin_amdgcn_mfma_f32_32x32x16_bf16(av, bv, e, 0, 0, 0);
    }
    const int p = pxt * 32 + px;
    const unsigned short* xl = &xp[p * KP + otile * 32 + (q2 << 2)];
#pragma unroll
    for (int rq = 0; rq < 4; ++rq) {
      u16x4 xq = *(const u16x4*)(xl + 8 * rq);
#pragma unroll
      for (int j = 0; j < 4; ++j) {
        const int r = rq * 4 + j;
        const int o = otile * 32 + j + (rq << 3) + (q2 << 2);
        const int gi = (b * 256 + o) * 4096 + s0 + p;
        __builtin_nontemporal_store(bf2f(xq[j]) + boutL[o] + e[r], &out[gi]);
      }
    }
  }
#undef PHASE
}

// =====================================================================
extern "C" void kernel_launch(void* const* d_in, const int* in_sizes, int n_in,
                              void* d_out, int out_size, void* d_ws, size_t ws_size,
                              hipStream_t stream) {
  const float* x    = (const float*)d_in[0];
  const float* pos  = (const float*)d_in[1];
  const float* wq   = (const float*)d_in[2];
  const float* bq   = (const float*)d_in[3];
  const float* wk   = (const float*)d_in[4];
  const float* bk   = (const float*)d_in[5];
  const float* v    = (const float*)d_in[6];
  const float* wout = (const float*)d_in[7];
  const float* bout = (const float*)d_in[8];
  float* out = (float*)d_out;
  unsigned short* wsp = (unsigned short*)d_ws;

  hipLaunchKernelGGL(prep_kernel, dim3(1536), dim3(256), 0, stream,
                     wq, bq, wk, bk, v, wout, wsp);
  hipLaunchKernelGGL(fused_kernel, dim3(256), dim3(1024), 0, stream,
                     x, pos, wsp, bout, out);
}

// Round 10
// 127.788 us; speedup vs baseline: 1.0226x; 1.0003x over previous
//
#include <hip/hip_runtime.h>
#include <stdint.h>

#define EPSN 1e-12f

typedef float f32x16 __attribute__((ext_vector_type(16)));
typedef float f32x4 __attribute__((ext_vector_type(4)));
typedef __bf16 bf16x8 __attribute__((ext_vector_type(8)));
typedef long long i64x2 __attribute__((ext_vector_type(2)));

// ---- bf16 helpers ----
__device__ __forceinline__ unsigned short f2bf(float f) {
  union { float f; unsigned int u; } v; v.f = f;
  unsigned int u = v.u + 0x7FFFu + ((v.u >> 16) & 1u);
  return (unsigned short)(u >> 16);
}

// f32 pair -> 2 OCP e4m3 bytes (RNE, HW convert)
__device__ __forceinline__ unsigned short f2fp8x2(float a, float b) {
  int r = __builtin_amdgcn_cvt_pk_fp8_f32(a, b, 0, false);
  return (unsigned short)(r & 0xFFFF);
}

// ---- workspace layout ----
// fp8 paired-tile fragment-major weights for 32x32x16 fp8 MFMA:
//   byte addr = ((pair*NKS + ks)*64 + hi*32 + col)*16 + t*8 + j
//   value = W[o = (2*pair+t)*32 + col][k = ks*16 + hi*8 + j]
//   (k=258 bias, >258 zero; K padded 258(+bias)->272)
#define NKS 17
#define WQF_B 0
#define WKF_B (16 * NKS * 64 * 16)          // 278528 B
#define WVP_OFF_S (2 * 16 * NKS * 64 * 8)   // ushort index 278528

// =====================================================================
// prep: blocks [0,512) pack wq/wk (4 o-rows each, fp8); [512,1536) WVt.
// =====================================================================
__global__ __launch_bounds__(256) void prep_kernel(
    const float* __restrict__ wq, const float* __restrict__ bq,
    const float* __restrict__ wk, const float* __restrict__ bk,
    const float* __restrict__ v, const float* __restrict__ wout,
    unsigned short* __restrict__ wsp) {
  uint8_t* wsp8 = (uint8_t*)wsp;
  int bid = blockIdx.x;
  if (bid < 512) {
    int isK = bid >= 256;
    int ob = (bid & 255) * 4;
    const float* w = isK ? wk : wq;
    const float* bb = isK ? bk : bq;
    uint8_t* dst = wsp8 + (isK ? WKF_B : WQF_B);
    for (int i = threadIdx.x; i < 4 * 129; i += 256) {
      int r = i / 129, q = i - r * 129;
      int o = ob + r, k = q * 2;
      float2 w2 = *(const float2*)(w + o * 258 + k);
      int g = o >> 5, col = o & 31, g2 = g >> 1, t = g & 1;
      int ks = k >> 4, hi = (k >> 3) & 1, j = k & 7;
      unsigned short pk = f2fp8x2(w2.x, w2.y);
      *(unsigned short*)(dst +
          (((g2 * NKS + ks) * 64 + hi * 32 + col) << 4) + t * 8 + j) = pk;
    }
    for (int i = threadIdx.x; i < 4 * 14; i += 256) {
      int r = i / 14, kk = 258 + (i - r * 14);
      int o = ob + r;
      int g = o >> 5, col = o & 31, g2 = g >> 1, t = g & 1;
      int ks = kk >> 4, hi = (kk >> 3) & 1, j = kk & 7;
      uint8_t val = (kk == 258) ? (uint8_t)(f2fp8x2(bb[o], 0.f) & 0xFF)
                                : (uint8_t)0;
      dst[(((g2 * NKS + ks) * 64 + hi * 32 + col) << 4) + t * 8 + j] = val;
    }
  } else {
    int idx = (bid - 512) * 256 + threadIdx.x;
    int fc = idx & 15, m = (idx >> 4) & 63, o = idx >> 10;
    const f32x4* wo = (const f32x4*)(wout + o * 256 + fc * 16);
    const f32x4* vm = (const f32x4*)(v + m * 256 + fc * 16);
    float s = 0.f;
#pragma unroll
    for (int f = 0; f < 4; ++f) {
      f32x4 a = wo[f], bvv = vm[f];
      s += a[0]*bvv[0] + a[1]*bvv[1] + a[2]*bvv[2] + a[3]*bvv[3];
    }
    s += __shfl_xor(s, 1, 64);
    s += __shfl_xor(s, 2, 64);
    s += __shfl_xor(s, 4, 64);
    s += __shfl_xor(s, 8, 64);
    if (fc == 0) wsp[WVP_OFF_S + o * 64 + m] = f2bf(s);
  }
}

// =====================================================================
// fused v10: fp8 Q/K GEMM. Per wave per K-step: ONE dwordx4 weight load
// (both tiles, 16B/lane) + two ds_read_b64 B-fragments. Per SIMD per
// step: 4 VMEM insts / 4 KB / 64 lines (was 16 / 32 KB / 512 lines).
// Rolled loop, depth-1 named prefetch. Epilogue: bf16 MFMA (attn@WVt),
// residual re-read from global (nt). absmax budget: fp8 affects only
// the small delta (~0.016 mag); x-residual path stays f32/bf16-clean.
// =====================================================================
#define PXB 64    // pixels per block
#define KP8 296   // xp8 row stride in BYTES (296%8==0; 2-way bank alias)
#define QS 66     // qbar row stride (floats)
#define AT 72     // attnM row stride (shorts)

__global__ __launch_bounds__(1024, 4) void fused_kernel(
    const float* __restrict__ x, const float* __restrict__ pos,
    const unsigned short* __restrict__ wsp, const float* __restrict__ bout,
    float* __restrict__ out) {
  __shared__ __align__(16) uint8_t xp8[PXB * KP8];             // 18944 B
  __shared__ __align__(16) float qbarL[16 * QS];               // 4224 B
  __shared__ __align__(16) unsigned short attnM[PXB * AT];     // 9216 B
  __shared__ float boutL[256];                                 // 1024 B

  const int tid = threadIdx.x;
  const int lane = tid & 63;
  const int wid = __builtin_amdgcn_readfirstlane(tid >> 6);
  const int px = lane & 31, q2 = lane >> 5;
  const int P0 = blockIdx.x * PXB;
  const int b = P0 >> 12, s0 = P0 & 4095;

  const uint8_t* wsp8 = (const uint8_t*)wsp;
  // Per-wave paired-tile stream base (pair = wid), +lane*16
  const uint8_t* wqf = wsp8 + WQF_B + wid * (NKS * 1024) + lane * 16;
  const uint8_t* wkf = wsp8 + WKF_B + wid * (NKS * 1024) + lane * 16;

  // ---- stage xp8[p][c] as fp8: f32x4 nt loads + HW cvt ----
  {
    const float* xrow = x + b * 256 * 4096 + s0;
    f32x4 lo[2], hi[2];
#pragma unroll
    for (int it = 0; it < 2; ++it) {
      int idx = tid + it * 1024;                  // 0..2047
      int g = idx & 15, dcol = idx >> 4;          // dcol 0..127
      lo[it] = __builtin_nontemporal_load(
          (const f32x4*)(xrow + (2 * dcol) * 4096 + 4 * g));
      hi[it] = __builtin_nontemporal_load(
          (const f32x4*)(xrow + (2 * dcol + 1) * 4096 + 4 * g));
    }
#pragma unroll
    for (int it = 0; it < 2; ++it) {
      int idx = tid + it * 1024;
      int g = idx & 15, dcol = idx >> 4;
#pragma unroll
      for (int j = 0; j < 4; ++j) {
        int pp = 4 * g + j;
        *(unsigned short*)&xp8[pp * KP8 + 2 * dcol] =
            f2fp8x2(lo[it][j], hi[it][j]);
      }
    }
    // tail: dcol 128 = (pos_y,pos_x), 129 = (1,0) bias, 130..135 = 0
    if (tid < 512) {
      int pp = tid & 63, dcol = 128 + (tid >> 6);
      float t0 = 0.f, t1 = 0.f;
      if (dcol == 128) { t0 = pos[s0 + pp]; t1 = pos[4096 + s0 + pp]; }
      else if (dcol == 129) { t0 = 1.0f; }
      *(unsigned short*)&xp8[pp * KP8 + 2 * dcol] = f2fp8x2(t0, t1);
    }
  }
  if (tid < 256) boutL[tid] = bout[tid];
  for (int i = tid; i < 16 * QS; i += 1024) qbarL[i] = 0.f;
  __syncthreads();

// Rolled K-loop, depth-1 named prefetch of the single paired fragment.
#define PHASE(WB) do {                                                    \
    const uint8_t* _p = (WB);                                             \
    const uint8_t* _b0p = &xp8[px * KP8 + q2 * 8];                        \
    const uint8_t* _b1p = &xp8[(32 + px) * KP8 + q2 * 8];                 \
    i64x2 _Ac = *(const i64x2*)_p;                                        \
    _Pragma("unroll 1")                                                   \
    for (int i = 0; i < NKS - 1; ++i) {                                   \
      i64x2 _An = *(const i64x2*)(_p + (i + 1) * 1024);                   \
      long long _b0 = *(const long long*)(_b0p + i * 16);                 \
      long long _b1 = *(const long long*)(_b1p + i * 16);                 \
      __builtin_amdgcn_s_setprio(1);                                      \
      acc00 = __builtin_amdgcn_mfma_f32_32x32x16_fp8_fp8(_Ac[0], _b0, acc00, 0, 0, 0); \
      acc01 = __builtin_amdgcn_mfma_f32_32x32x16_fp8_fp8(_Ac[0], _b1, acc01, 0, 0, 0); \
      acc10 = __builtin_amdgcn_mfma_f32_32x32x16_fp8_fp8(_Ac[1], _b0, acc10, 0, 0, 0); \
      acc11 = __builtin_amdgcn_mfma_f32_32x32x16_fp8_fp8(_Ac[1], _b1, acc11, 0, 0, 0); \
      __builtin_amdgcn_s_setprio(0);                                      \
      _Ac = _An;                                                          \
    }                                                                     \
    {                                                                     \
      long long _b0 = *(const long long*)(_b0p + (NKS - 1) * 16);         \
      long long _b1 = *(const long long*)(_b1p + (NKS - 1) * 16);         \
      acc00 = __builtin_amdgcn_mfma_f32_32x32x16_fp8_fp8(_Ac[0], _b0, acc00, 0, 0, 0); \
      acc01 = __builtin_amdgcn_mfma_f32_32x32x16_fp8_fp8(_Ac[0], _b1, acc01, 0, 0, 0); \
      acc10 = __builtin_amdgcn_mfma_f32_32x32x16_fp8_fp8(_Ac[1], _b0, acc10, 0, 0, 0); \
      acc11 = __builtin_amdgcn_mfma_f32_32x32x16_fp8_fp8(_Ac[1], _b1, acc11, 0, 0, 0); \
    }                                                                     \
  } while (0)

  // ================= q phase =================
  f32x16 acc00 = (f32x16)0.f, acc01 = (f32x16)0.f,
         acc10 = (f32x16)0.f, acc11 = (f32x16)0.f;
  PHASE(wqf);

  // normalize per m; accumulate qbar partials
  {
    float qsum[2][8];
#pragma unroll
    for (int nt = 0; nt < 2; ++nt)
#pragma unroll
      for (int r = 0; r < 8; ++r) qsum[nt][r] = 0.f;
#pragma unroll
    for (int ot = 0; ot < 2; ++ot) {
#pragma unroll
      for (int nt = 0; nt < 2; ++nt) {
        const f32x16 a = ot ? (nt ? acc11 : acc10) : (nt ? acc01 : acc00);
        float s20 = 0.f, s21 = 0.f;
#pragma unroll
        for (int r = 0; r < 8; ++r) {
          s20 = fmaf(a[r], a[r], s20);
          s21 = fmaf(a[r + 8], a[r + 8], s21);
        }
        s20 += __shfl_xor(s20, 32, 64);
        s21 += __shfl_xor(s21, 32, 64);
        float i0 = 1.0f / fmaxf(sqrtf(s20), EPSN);
        float i1 = 1.0f / fmaxf(sqrtf(s21), EPSN);
#pragma unroll
        for (int r = 0; r < 8; ++r) qsum[nt][r] += a[r] * i0 + a[r + 8] * i1;
      }
    }
#pragma unroll
    for (int nt = 0; nt < 2; ++nt)
#pragma unroll
      for (int r = 0; r < 8; ++r) {
        int j = (r & 3) + ((r >> 2) << 3) + (q2 << 2);
        atomicAdd(&qbarL[j * QS + nt * 32 + px], qsum[nt][r] * (1.0f / 64.0f));
      }
  }
  // NO barrier here: k-phase MFMAs don't read qbarL; the barrier below
  // (after the k K-loop) orders the qbar atomics vs the qb reads.

  // ================= k phase =================
  acc00 = (f32x16)0.f; acc01 = (f32x16)0.f;
  acc10 = (f32x16)0.f; acc11 = (f32x16)0.f;
  PHASE(wkf);
  __syncthreads();

  {
    float qb[2][8];
#pragma unroll
    for (int nt = 0; nt < 2; ++nt)
#pragma unroll
      for (int r = 0; r < 8; ++r) {
        int j = (r & 3) + ((r >> 2) << 3) + (q2 << 2);
        qb[nt][r] = qbarL[j * QS + nt * 32 + px];
      }
#pragma unroll
    for (int ot = 0; ot < 2; ++ot) {
#pragma unroll
      for (int nt = 0; nt < 2; ++nt) {
        const f32x16 a = ot ? (nt ? acc11 : acc10) : (nt ? acc01 : acc00);
        float s20 = 0.f, s21 = 0.f, sp0 = 0.f, sp1 = 0.f;
#pragma unroll
        for (int r = 0; r < 8; ++r) {
          s20 = fmaf(a[r], a[r], s20);         sp0 = fmaf(qb[nt][r], a[r], sp0);
          s21 = fmaf(a[r + 8], a[r + 8], s21); sp1 = fmaf(qb[nt][r], a[r + 8], sp1);
        }
        s20 += __shfl_xor(s20, 32, 64);
        s21 += __shfl_xor(s21, 32, 64);
        sp0 += __shfl_xor(sp0, 32, 64);
        sp1 += __shfl_xor(sp1, 32, 64);
        if (q2 == 0) {
          int m0 = wid * 4 + ot * 2;
          attnM[(nt * 32 + px) * AT + m0]     = f2bf(sp0 / fmaxf(sqrtf(s20), EPSN));
          attnM[(nt * 32 + px) * AT + m0 + 1] = f2bf(sp1 / fmaxf(sqrtf(s21), EPSN));
        }
      }
    }
  }
  __syncthreads();

  // ==== epilogue: out = x + bout + WVt @ attn (x nt-reload; nt stores) ====
  {
    const int otile = wid >> 1, pxt = wid & 1;
    f32x16 e = (f32x16)0.f;
    const unsigned short* wv =
        wsp + WVP_OFF_S + (otile * 32 + px) * 64 + q2 * 8;
    const unsigned short* ab = &attnM[(pxt * 32 + px) * AT + q2 * 8];
#pragma unroll
    for (int ks = 0; ks < 4; ++ks) {
      bf16x8 av = *(const bf16x8*)(wv + ks * 16);
      bf16x8 bv = *(const bf16x8*)(ab + ks * 16);
      e = __builtin_amdgcn_mfma_f32_32x32x16_bf16(av, bv, e, 0, 0, 0);
    }
    const int p = pxt * 32 + px;
#pragma unroll
    for (int r = 0; r < 16; ++r) {
      const int o = otile * 32 + (r & 3) + ((r >> 2) << 3) + (q2 << 2);
      const int gi = (b * 256 + o) * 4096 + s0 + p;
      float xv = __builtin_nontemporal_load(&x[gi]);
      __builtin_nontemporal_store(xv + boutL[o] + e[r], &out[gi]);
    }
  }
#undef PHASE
}

// =====================================================================
extern "C" void kernel_launch(void* const* d_in, const int* in_sizes, int n_in,
                              void* d_out, int out_size, void* d_ws, size_t ws_size,
                              hipStream_t stream) {
  const float* x    = (const float*)d_in[0];
  const float* pos  = (const float*)d_in[1];
  const float* wq   = (const float*)d_in[2];
  const float* bq   = (const float*)d_in[3];
  const float* wk   = (const float*)d_in[4];
  const float* bk   = (const float*)d_in[5];
  const float* v    = (const float*)d_in[6];
  const float* wout = (const float*)d_in[7];
  const float* bout = (const float*)d_in[8];
  float* out = (float*)d_out;
  unsigned short* wsp = (unsigned short*)d_ws;

  hipLaunchKernelGGL(prep_kernel, dim3(1536), dim3(256), 0, stream,
                     wq, bq, wk, bk, v, wout, wsp);
  hipLaunchKernelGGL(fused_kernel, dim3(256), dim3(1024), 0, stream,
                     x, pos, wsp, bout, out);
}